// Round 12
// baseline (197.373 us; speedup 1.0000x reference)
//
#include <hip/hip_runtime.h>

#define C_LENX 2048
#define Q_LENX 512
#define BATCH  32
#define HDIM   256
#define BH     8192
#define CBLK   128            // 8 waves x 16 c-rows
#define QBLK   32
#define NQT    16
#define NWAVES 8
#define TILE_BYTES 32768      // qf 16K (fp16[32][256], swz) + qt 16K (fp16[256][32], swz)
#define OFF_QT 16384

typedef __attribute__((ext_vector_type(8))) _Float16 f16x8;
typedef __attribute__((ext_vector_type(4))) float f32x4;

__device__ __forceinline__ unsigned short f2h_bits(float x) {
    union { _Float16 h; unsigned short u; } cv;
    cv.h = (_Float16)x;                     // RTNE
    return cv.u;
}
__device__ __forceinline__ float h2f_bits(unsigned short u) {
    union { unsigned short u; _Float16 h; } cv;
    cv.u = u;
    return (float)cv.h;
}

// async global->LDS, 16B per lane, wave-uniform LDS base + lane*16
__device__ __forceinline__ void stage16(const void* gsrc, void* ldst) {
    __builtin_amdgcn_global_load_lds(
        (const __attribute__((address_space(1))) unsigned int*)gsrc,
        (__attribute__((address_space(3))) unsigned int*)ldst, 16, 0, 0);
}

// ---------------- prep: fp32 Q -> fp16 blob (exact swizzled LDS images) ----------------
// qf: row q (512B); 16B chunk c at byte q*512 + 16*(c ^ (q&7))     [holds Q[q][8c..8c+7]]
// qt: chunk m = h*4 + qc (qc = q/8) at byte OFF_QT + 16*(m ^ ((m>>3)&7))
__global__ __launch_bounds__(256)
void q_prep(const float* __restrict__ question, unsigned char* __restrict__ blob)
{
    __shared__ unsigned short sHf[QBLK][264];
    const int tid = threadIdx.x;
    const int b  = blockIdx.x >> 4;
    const int t  = blockIdx.x & 15;
    const float* qbase = question + (size_t)(t * QBLK) * BH + b * HDIM;
    unsigned char* tb = blob + (size_t)(b * NQT + t) * TILE_BYTES;

    #pragma unroll
    for (int i = 0; i < 8; ++i) {
        int e  = tid + i * 256;          // float4 cell 0..2047
        int qr = e >> 6;                 // 0..31
        int h4 = (e & 63) << 2;          // 0..252
        float4 x = *reinterpret_cast<const float4*>(qbase + (size_t)qr * BH + h4);
        ushort4 hv;
        hv.x = f2h_bits(x.x); hv.y = f2h_bits(x.y);
        hv.z = f2h_bits(x.z); hv.w = f2h_bits(x.w);
        *reinterpret_cast<ushort4*>(&sHf[qr][h4]) = hv;
        int c = h4 >> 3;                 // 16B chunk within row
        *reinterpret_cast<ushort4*>(tb + qr * 512 + ((c ^ (qr & 7)) << 4) + ((h4 & 7) << 1)) = hv;
    }
    __syncthreads();
    #pragma unroll
    for (int i = 0; i < 8; ++i) {
        int e  = tid + i * 256;          // ushort4 cell of qt, 0..2047
        int h  = e >> 3;                 // 0..255
        int q4 = (e & 7) << 2;           // 0..28
        ushort4 v;
        v.x = sHf[q4 + 0][h]; v.y = sHf[q4 + 1][h];
        v.z = sHf[q4 + 2][h]; v.w = sHf[q4 + 3][h];
        int m  = h * 4 + (q4 >> 3);
        int ms = m ^ ((m >> 3) & 7);
        *reinterpret_cast<ushort4*>(tb + OFF_QT + (ms << 4) + ((q4 & 4) << 1)) = v;
    }
}

// ------- main: R10 structure, 512-thread blocks (8 waves share the 64KB dbuf) -------
__global__ __launch_bounds__(512, 4)
void s2s_attn(const float* __restrict__ content,
              const unsigned char* __restrict__ blob,
              const int*   __restrict__ qmask,
              float*       __restrict__ out)
{
    __shared__ __attribute__((aligned(16))) unsigned char sBuf[2 * TILE_BYTES];

    const int tid  = threadIdx.x;
    const int wid  = tid >> 6;           // 0..7
    const int lane = tid & 63;
    const int lr   = lane & 15;
    const int lg   = lane >> 4;

    // XCD-aware swizzle: 512 blocks, 64 per XCD = 4 complete batches (blob L2 locality)
    const int lin = (blockIdx.x & 7) * 64 + (blockIdx.x >> 3);
    const int ct = lin & 15;             // 16 c-tiles per batch
    const int b  = lin >> 4;
    const int c0 = ct * CBLK;

    // prologue: DMA tile 0 into buffer 0 (32 segs of 1KB; 4 per wave)
    {
        const unsigned char* tb0 = blob + (size_t)(b * NQT) * TILE_BYTES;
        #pragma unroll
        for (int j = 0; j < 4; ++j) {
            int seg = wid * 4 + j;
            stage16(tb0 + seg * 1024 + lane * 16, sBuf + seg * 1024);
        }
    }

    // content preload: 16 c-rows as SINGLE fp16 fragments (A/B-frag layout: row=lr, k=lg*8)
    f16x8 chi[8];
    {
        const float* cbase = content + (size_t)(c0 + wid*16 + lr) * BH + b*HDIM + lg*8;
        #pragma unroll
        for (int kc = 0; kc < 8; ++kc) {
            float4 x0 = *reinterpret_cast<const float4*>(cbase + kc*32);
            float4 x1 = *reinterpret_cast<const float4*>(cbase + kc*32 + 4);
            float xs[8] = {x0.x,x0.y,x0.z,x0.w,x1.x,x1.y,x1.z,x1.w};
            #pragma unroll
            for (int j = 0; j < 8; ++j)
                chi[kc][j] = (_Float16)xs[j];
        }
    }

    f32x4 acc[16];
    #pragma unroll
    for (int n = 0; n < 16; ++n) { f32x4 z = {0.f,0.f,0.f,0.f}; acc[n] = z; }
    float m_run = -INFINITY;   // softmax state for c-row lr (replicated on 4 lanes)
    float l_run = 0.f;

    __syncthreads();           // tile 0 DMA drained + visible

    for (int t = 0; t < NQT; ++t) {
        const unsigned char* qf = sBuf + (t & 1) * TILE_BYTES;
        const unsigned char* qt = qf + OFF_QT;

        // T3 2-phase: issue next tile's DMA into the other buffer, compute, one barrier
        if (t + 1 < NQT) {
            const unsigned char* tbn = blob + (size_t)(b * NQT + t + 1) * TILE_BYTES;
            unsigned char* db = sBuf + ((t + 1) & 1) * TILE_BYTES;
            #pragma unroll
            for (int j = 0; j < 4; ++j) {
                int seg = wid * 4 + j;
                stage16(tbn + seg * 1024 + lane * 16, db + seg * 1024);
            }
        }
        const unsigned mw = (unsigned)__ballot(qmask[b * Q_LENX + t * QBLK + (lane & 31)] != 0);

        // ---- swapped QK^T: S^T = mfma(A=Q, B=C); 2 independent chains, single fp16 ----
        f32x4 zz = {0.f,0.f,0.f,0.f};
        f32x4 sacc0 = zz, sacc1 = zz;
        const unsigned swz = (unsigned)(lr & 7);   // (16+lr)&7 == lr&7
        __builtin_amdgcn_s_setprio(1);
        #pragma unroll
        for (int kc = 0; kc < 8; ++kc) {
            unsigned off = (unsigned)((kc*4 + lg) ^ swz) << 4;
            f16x8 qf0 = *reinterpret_cast<const f16x8*>(qf + lr*512 + off);
            f16x8 qf1 = *reinterpret_cast<const f16x8*>(qf + (16+lr)*512 + off);
            sacc0 = __builtin_amdgcn_mfma_f32_16x16x32_f16(qf0, chi[kc], sacc0, 0, 0, 0);
            sacc1 = __builtin_amdgcn_mfma_f32_16x16x32_f16(qf1, chi[kc], sacc1, 0, 0, 0);
        }
        __builtin_amdgcn_s_setprio(0);
        // sacc0: rows q=lg*4+r, col c=lr;  sacc1: rows q=16+lg*4+r, col c=lr

        // ---- per-lane softmax for c-row lr (reduce over lanes lr, lr+16, lr+32, lr+48) ----
        float p[8];
        float tmax = -INFINITY;
        #pragma unroll
        for (int r = 0; r < 4; ++r) {
            float v0 = ((mw >> (lg*4 + r))      & 1u) ? sacc0[r] : -INFINITY;
            float v1 = ((mw >> (16 + lg*4 + r)) & 1u) ? sacc1[r] : -INFINITY;
            p[r] = v0; p[4 + r] = v1;
            tmax = fmaxf(tmax, fmaxf(v0, v1));
        }
        tmax = fmaxf(tmax, __shfl_xor(tmax, 16, 64));
        tmax = fmaxf(tmax, __shfl_xor(tmax, 32, 64));

        if (__ballot(tmax > m_run + 4.0f)) {   // T13 defer-max, wave-uniform
            float mnew = fmaxf(m_run, tmax);
            float scale = 1.f;
            if (mnew != -INFINITY) { scale = __expf(m_run - mnew); m_run = mnew; }
            l_run *= scale;
            float sc0 = __shfl(scale, lg*4 + 0, 16);
            float sc1 = __shfl(scale, lg*4 + 1, 16);
            float sc2 = __shfl(scale, lg*4 + 2, 16);
            float sc3 = __shfl(scale, lg*4 + 3, 16);
            #pragma unroll
            for (int n = 0; n < 16; ++n) {
                acc[n][0] *= sc0; acc[n][1] *= sc1;
                acc[n][2] *= sc2; acc[n][3] *= sc3;
            }
        }

        unsigned short pb[8];
        float psum = 0.f;
        if (m_run == -INFINITY) {
            #pragma unroll
            for (int i = 0; i < 8; ++i) pb[i] = 0;
        } else {
            #pragma unroll
            for (int i = 0; i < 8; ++i) {
                float e = __expf(p[i] - m_run);    // bounded by e^4
                pb[i] = f2h_bits(e);
                psum += h2f_bits(pb[i]);           // sum ROUNDED weights
            }
        }
        psum += __shfl_xor(psum, 16, 64);
        psum += __shfl_xor(psum, 32, 64);
        l_run += psum;

        // ---- P redistribution in-register (no LDS) ----
        unsigned d0 = (unsigned)pb[0] | ((unsigned)pb[1] << 16);
        unsigned d1 = (unsigned)pb[2] | ((unsigned)pb[3] << 16);
        unsigned d2 = (unsigned)pb[4] | ((unsigned)pb[5] << 16);
        unsigned d3 = (unsigned)pb[6] | ((unsigned)pb[7] << 16);
        int srcA = ((2*lg) & 3) * 16 + lr;
        int srcB = srcA + 16;
        bool hi = (lg >= 2);
        unsigned a0 = (unsigned)__shfl((int)d0, srcA, 64);
        unsigned a1 = (unsigned)__shfl((int)d1, srcA, 64);
        unsigned a2 = (unsigned)__shfl((int)d2, srcA, 64);
        unsigned a3 = (unsigned)__shfl((int)d3, srcA, 64);
        unsigned b0 = (unsigned)__shfl((int)d0, srcB, 64);
        unsigned b1 = (unsigned)__shfl((int)d1, srcB, 64);
        unsigned b2 = (unsigned)__shfl((int)d2, srcB, 64);
        unsigned b3 = (unsigned)__shfl((int)d3, srcB, 64);
        union { unsigned u[4]; f16x8 v; } pu;
        pu.u[0] = hi ? a2 : a0;
        pu.u[1] = hi ? a3 : a1;
        pu.u[2] = hi ? b2 : b0;
        pu.u[3] = hi ? b3 : b1;
        f16x8 pfrag = pu.v;

        // ---- PV: acc[16 c x 256 h] += P(16x32) * Q(32x256), fp16 ----
        __builtin_amdgcn_s_setprio(1);
        #pragma unroll
        for (int n = 0; n < 16; ++n) {
            int h = n*16 + lr;
            int m = h*4 + lg;
            int ms = m ^ ((m >> 3) & 7);
            f16x8 vfrag = *reinterpret_cast<const f16x8*>(qt + (ms << 4));
            acc[n] = __builtin_amdgcn_mfma_f32_16x16x32_f16(pfrag, vfrag, acc[n], 0, 0, 0);
        }
        __builtin_amdgcn_s_setprio(0);

        __syncthreads();   // all waves done with tile t; next tile's DMA drained
    }

    // ---- epilogue: broadcast 1/l_run (per c=lr) into acc domain, normalize, store ----
    float linv = 1.f / l_run;
    float rinv[4];
    rinv[0] = __shfl(linv, lg*4 + 0, 16);
    rinv[1] = __shfl(linv, lg*4 + 1, 16);
    rinv[2] = __shfl(linv, lg*4 + 2, 16);
    rinv[3] = __shfl(linv, lg*4 + 3, 16);
    float* obase = out + (size_t)(c0 + wid*16) * BH + b*HDIM;
    #pragma unroll
    for (int n = 0; n < 16; ++n) {
        #pragma unroll
        for (int r = 0; r < 4; ++r)
            obase[(size_t)(lg*4 + r) * BH + n*16 + lr] = acc[n][r] * rinv[r];
    }
}

extern "C" void kernel_launch(void* const* d_in, const int* in_sizes, int n_in,
                              void* d_out, int out_size, void* d_ws, size_t ws_size,
                              hipStream_t stream) {
    const float* content  = (const float*)d_in[0];
    const float* question = (const float*)d_in[1];
    const int*   mask     = (const int*)d_in[2];
    float*       out      = (float*)d_out;

    unsigned char* blob = (unsigned char*)d_ws;   // 512 tiles * 32KB = 16 MB

    q_prep<<<BATCH * NQT, 256, 0, stream>>>(question, blob);
    s2s_attn<<<C_LENX / CBLK * BATCH, 512, 0, stream>>>(content, blob, mask, out);
}

// Round 13
// 88.901 us; speedup vs baseline: 2.2201x; 2.2201x over previous
//
#include <hip/hip_runtime.h>

#define C_LENX 2048
#define Q_LENX 512
#define BATCH  32
#define HDIM   256
#define BH     8192
#define CBLK   64
#define QBLK   32
#define NQT    16
#define NWAVES 4
#define TILE_BYTES 32768      // qf 16K (fp16[32][256], swz) + qt 16K (fp16[256][32], swz)
#define OFF_QT 16384

typedef __attribute__((ext_vector_type(8))) _Float16 f16x8;
typedef __attribute__((ext_vector_type(4))) float f32x4;

__device__ __forceinline__ unsigned short f2h_bits(float x) {
    union { _Float16 h; unsigned short u; } cv;
    cv.h = (_Float16)x;                     // RTNE
    return cv.u;
}
__device__ __forceinline__ float h2f_bits(unsigned short u) {
    union { unsigned short u; _Float16 h; } cv;
    cv.u = u;
    return (float)cv.h;
}

// async global->LDS, 16B per lane, wave-uniform LDS base + lane*16
__device__ __forceinline__ void stage16(const void* gsrc, void* ldst) {
    __builtin_amdgcn_global_load_lds(
        (const __attribute__((address_space(1))) unsigned int*)gsrc,
        (__attribute__((address_space(3))) unsigned int*)ldst, 16, 0, 0);
}

// ---------------- prep: fp32 Q -> fp16 blob (exact swizzled LDS images) ----------------
// qf: row q (512B); 16B chunk c at byte q*512 + 16*(c ^ (q&7))     [holds Q[q][8c..8c+7]]
// qt: chunk m = h*4 + qc (qc = q/8) at byte OFF_QT + 16*(m ^ ((m>>3)&7))
__global__ __launch_bounds__(256)
void q_prep(const float* __restrict__ question, unsigned char* __restrict__ blob)
{
    __shared__ unsigned short sHf[QBLK][264];
    const int tid = threadIdx.x;
    const int b  = blockIdx.x >> 4;
    const int t  = blockIdx.x & 15;
    const float* qbase = question + (size_t)(t * QBLK) * BH + b * HDIM;
    unsigned char* tb = blob + (size_t)(b * NQT + t) * TILE_BYTES;

    #pragma unroll
    for (int i = 0; i < 8; ++i) {
        int e  = tid + i * 256;          // float4 cell 0..2047
        int qr = e >> 6;                 // 0..31
        int h4 = (e & 63) << 2;          // 0..252
        float4 x = *reinterpret_cast<const float4*>(qbase + (size_t)qr * BH + h4);
        ushort4 hv;
        hv.x = f2h_bits(x.x); hv.y = f2h_bits(x.y);
        hv.z = f2h_bits(x.z); hv.w = f2h_bits(x.w);
        *reinterpret_cast<ushort4*>(&sHf[qr][h4]) = hv;
        int c = h4 >> 3;                 // 16B chunk within row
        *reinterpret_cast<ushort4*>(tb + qr * 512 + ((c ^ (qr & 7)) << 4) + ((h4 & 7) << 1)) = hv;
    }
    __syncthreads();
    #pragma unroll
    for (int i = 0; i < 8; ++i) {
        int e  = tid + i * 256;          // ushort4 cell of qt, 0..2047
        int h  = e >> 3;                 // 0..255
        int q4 = (e & 7) << 2;           // 0..28
        ushort4 v;
        v.x = sHf[q4 + 0][h]; v.y = sHf[q4 + 1][h];
        v.z = sHf[q4 + 2][h]; v.w = sHf[q4 + 3][h];
        int m  = h * 4 + (q4 >> 3);
        int ms = m ^ ((m >> 3) & 7);
        *reinterpret_cast<ushort4*>(tb + OFF_QT + (ms << 4) + ((q4 & 4) << 1)) = v;
    }
}

// -------- main: R10 + hoisted PV loads (overlap softmax) + 4-chain QK^T --------
__global__ __launch_bounds__(256, 2)
void s2s_attn(const float* __restrict__ content,
              const unsigned char* __restrict__ blob,
              const int*   __restrict__ qmask,
              float*       __restrict__ out)
{
    __shared__ __attribute__((aligned(16))) unsigned char sBuf[2 * TILE_BYTES];

    const int tid  = threadIdx.x;
    const int wid  = tid >> 6;
    const int lane = tid & 63;
    const int lr   = lane & 15;
    const int lg   = lane >> 4;

    // XCD-aware swizzle: each XCD owns 4 complete batches (blob L2 locality)
    const int lin = (blockIdx.x & 7) * 128 + (blockIdx.x >> 3);
    const int ct = lin & 31;
    const int b  = lin >> 5;
    const int c0 = ct * CBLK;

    // prologue: DMA tile 0 into buffer 0 (32 segs of 1KB; 8 per wave)
    {
        const unsigned char* tb0 = blob + (size_t)(b * NQT) * TILE_BYTES;
        #pragma unroll
        for (int j = 0; j < 8; ++j) {
            int seg = wid * 8 + j;
            stage16(tb0 + seg * 1024 + lane * 16, sBuf + seg * 1024);
        }
    }

    // content preload: 16 c-rows as single fp16 fragments (A/B-frag layout: row=lr, k=lg*8)
    f16x8 chi[8];
    {
        const float* cbase = content + (size_t)(c0 + wid*16 + lr) * BH + b*HDIM + lg*8;
        #pragma unroll
        for (int kc = 0; kc < 8; ++kc) {
            float4 x0 = *reinterpret_cast<const float4*>(cbase + kc*32);
            float4 x1 = *reinterpret_cast<const float4*>(cbase + kc*32 + 4);
            float xs[8] = {x0.x,x0.y,x0.z,x0.w,x1.x,x1.y,x1.z,x1.w};
            #pragma unroll
            for (int j = 0; j < 8; ++j)
                chi[kc][j] = (_Float16)xs[j];
        }
    }

    f32x4 acc[16];
    #pragma unroll
    for (int n = 0; n < 16; ++n) { f32x4 z = {0.f,0.f,0.f,0.f}; acc[n] = z; }
    float m_run = -INFINITY;   // softmax state for c-row lr (replicated on 4 lanes)
    float l_run = 0.f;

    __syncthreads();           // tile 0 DMA drained + visible

    for (int t = 0; t < NQT; ++t) {
        const unsigned char* qf = sBuf + (t & 1) * TILE_BYTES;
        const unsigned char* qt = qf + OFF_QT;

        // T3 2-phase: issue next tile's DMA into the other buffer, compute, one barrier
        if (t + 1 < NQT) {
            const unsigned char* tbn = blob + (size_t)(b * NQT + t + 1) * TILE_BYTES;
            unsigned char* db = sBuf + ((t + 1) & 1) * TILE_BYTES;
            #pragma unroll
            for (int j = 0; j < 8; ++j) {
                int seg = wid * 8 + j;
                stage16(tbn + seg * 1024 + lane * 16, db + seg * 1024);
            }
        }
        const unsigned mw = (unsigned)__ballot(qmask[b * Q_LENX + t * QBLK + (lane & 31)] != 0);

        // ---- swapped QK^T: S^T = mfma(A=Q, B=C); 4 independent chains (depth 4) ----
        f32x4 zz = {0.f,0.f,0.f,0.f};
        f32x4 s0a=zz, s0b=zz, s1a=zz, s1b=zz;
        const unsigned swz = (unsigned)(lr & 7);   // (16+lr)&7 == lr&7
        __builtin_amdgcn_s_setprio(1);
        #pragma unroll
        for (int kc = 0; kc < 8; kc += 2) {
            unsigned offA = (unsigned)((kc*4 + lg) ^ swz) << 4;
            unsigned offB = (unsigned)(((kc+1)*4 + lg) ^ swz) << 4;
            f16x8 qa0 = *reinterpret_cast<const f16x8*>(qf + lr*512 + offA);
            f16x8 qa1 = *reinterpret_cast<const f16x8*>(qf + (16+lr)*512 + offA);
            f16x8 qb0 = *reinterpret_cast<const f16x8*>(qf + lr*512 + offB);
            f16x8 qb1 = *reinterpret_cast<const f16x8*>(qf + (16+lr)*512 + offB);
            s0a = __builtin_amdgcn_mfma_f32_16x16x32_f16(qa0, chi[kc],   s0a, 0, 0, 0);
            s1a = __builtin_amdgcn_mfma_f32_16x16x32_f16(qa1, chi[kc],   s1a, 0, 0, 0);
            s0b = __builtin_amdgcn_mfma_f32_16x16x32_f16(qb0, chi[kc+1], s0b, 0, 0, 0);
            s1b = __builtin_amdgcn_mfma_f32_16x16x32_f16(qb1, chi[kc+1], s1b, 0, 0, 0);
        }
        __builtin_amdgcn_s_setprio(0);
        f32x4 sacc0 = s0a + s0b;   // rows q=lg*4+r,    col c=lr
        f32x4 sacc1 = s1a + s1b;   // rows q=16+lg*4+r, col c=lr

        // ---- hoisted PV B-operand loads: depend only on qt(t), overlap softmax below ----
        f16x8 vf[16];
        #pragma unroll
        for (int n = 0; n < 16; ++n) {
            int h = n*16 + lr;
            int m = h*4 + lg;
            int ms = m ^ ((m >> 3) & 7);
            vf[n] = *reinterpret_cast<const f16x8*>(qt + (ms << 4));
        }

        // ---- per-lane softmax for c-row lr (reduce over lanes lr, lr+16, lr+32, lr+48) ----
        float p[8];
        float tmax = -INFINITY;
        #pragma unroll
        for (int r = 0; r < 4; ++r) {
            float v0 = ((mw >> (lg*4 + r))      & 1u) ? sacc0[r] : -INFINITY;
            float v1 = ((mw >> (16 + lg*4 + r)) & 1u) ? sacc1[r] : -INFINITY;
            p[r] = v0; p[4 + r] = v1;
            tmax = fmaxf(tmax, fmaxf(v0, v1));
        }
        tmax = fmaxf(tmax, __shfl_xor(tmax, 16, 64));
        tmax = fmaxf(tmax, __shfl_xor(tmax, 32, 64));

        if (__ballot(tmax > m_run + 4.0f)) {   // T13 defer-max, wave-uniform
            float mnew = fmaxf(m_run, tmax);
            float scale = 1.f;
            if (mnew != -INFINITY) { scale = __expf(m_run - mnew); m_run = mnew; }
            l_run *= scale;
            float sc0 = __shfl(scale, lg*4 + 0, 16);
            float sc1 = __shfl(scale, lg*4 + 1, 16);
            float sc2 = __shfl(scale, lg*4 + 2, 16);
            float sc3 = __shfl(scale, lg*4 + 3, 16);
            #pragma unroll
            for (int n = 0; n < 16; ++n) {
                acc[n][0] *= sc0; acc[n][1] *= sc1;
                acc[n][2] *= sc2; acc[n][3] *= sc3;
            }
        }

        unsigned short pb[8];
        float psum = 0.f;
        if (m_run == -INFINITY) {
            #pragma unroll
            for (int i = 0; i < 8; ++i) pb[i] = 0;
        } else {
            #pragma unroll
            for (int i = 0; i < 8; ++i) {
                float e = __expf(p[i] - m_run);    // bounded by e^4
                pb[i] = f2h_bits(e);
                psum += h2f_bits(pb[i]);           // sum ROUNDED weights
            }
        }
        psum += __shfl_xor(psum, 16, 64);
        psum += __shfl_xor(psum, 32, 64);
        l_run += psum;

        // ---- P redistribution in-register (no LDS) ----
        unsigned d0 = (unsigned)pb[0] | ((unsigned)pb[1] << 16);
        unsigned d1 = (unsigned)pb[2] | ((unsigned)pb[3] << 16);
        unsigned d2 = (unsigned)pb[4] | ((unsigned)pb[5] << 16);
        unsigned d3 = (unsigned)pb[6] | ((unsigned)pb[7] << 16);
        int srcA = ((2*lg) & 3) * 16 + lr;
        int srcB = srcA + 16;
        bool hi = (lg >= 2);
        unsigned a0 = (unsigned)__shfl((int)d0, srcA, 64);
        unsigned a1 = (unsigned)__shfl((int)d1, srcA, 64);
        unsigned a2 = (unsigned)__shfl((int)d2, srcA, 64);
        unsigned a3 = (unsigned)__shfl((int)d3, srcA, 64);
        unsigned b0 = (unsigned)__shfl((int)d0, srcB, 64);
        unsigned b1 = (unsigned)__shfl((int)d1, srcB, 64);
        unsigned b2 = (unsigned)__shfl((int)d2, srcB, 64);
        unsigned b3 = (unsigned)__shfl((int)d3, srcB, 64);
        union { unsigned u[4]; f16x8 v; } pu;
        pu.u[0] = hi ? a2 : a0;
        pu.u[1] = hi ? a3 : a1;
        pu.u[2] = hi ? b2 : b0;
        pu.u[3] = hi ? b3 : b1;
        f16x8 pfrag = pu.v;

        // ---- PV: acc[16 c x 256 h] += P(16x32) * Q(32x256); vf preloaded ----
        __builtin_amdgcn_s_setprio(1);
        #pragma unroll
        for (int n = 0; n < 16; ++n)
            acc[n] = __builtin_amdgcn_mfma_f32_16x16x32_f16(pfrag, vf[n], acc[n], 0, 0, 0);
        __builtin_amdgcn_s_setprio(0);

        __syncthreads();   // all waves done with tile t; next tile's DMA drained
    }

    // ---- epilogue: broadcast 1/l_run (per c=lr) into acc domain, normalize, store ----
    float linv = 1.f / l_run;
    float rinv[4];
    rinv[0] = __shfl(linv, lg*4 + 0, 16);
    rinv[1] = __shfl(linv, lg*4 + 1, 16);
    rinv[2] = __shfl(linv, lg*4 + 2, 16);
    rinv[3] = __shfl(linv, lg*4 + 3, 16);
    float* obase = out + (size_t)(c0 + wid*16) * BH + b*HDIM;
    #pragma unroll
    for (int n = 0; n < 16; ++n) {
        #pragma unroll
        for (int r = 0; r < 4; ++r)
            obase[(size_t)(lg*4 + r) * BH + n*16 + lr] = acc[n][r] * rinv[r];
    }
}

extern "C" void kernel_launch(void* const* d_in, const int* in_sizes, int n_in,
                              void* d_out, int out_size, void* d_ws, size_t ws_size,
                              hipStream_t stream) {
    const float* content  = (const float*)d_in[0];
    const float* question = (const float*)d_in[1];
    const int*   mask     = (const int*)d_in[2];
    float*       out      = (float*)d_out;

    unsigned char* blob = (unsigned char*)d_ws;   // 512 tiles * 32KB = 16 MB

    q_prep<<<BATCH * NQT, 256, 0, stream>>>(question, blob);
    s2s_attn<<<C_LENX / CBLK * BATCH, 256, 0, stream>>>(content, blob, mask, out);
}